// Round 15
// baseline (236.964 us; speedup 1.0000x reference)
//
#include <hip/hip_runtime.h>

// B=32, C=64, H=W=112. Per-sample 3x3 convs via bf16 MFMA implicit GEMM.
// Image format: per-sample ZERO-PADDED half-planes [b][half(ci32)][slot][32ci],
// slot = POFF + y*113 + x; col 112 of each row = shared zero border; 128 zero
// slots lead, 273 trail. PIXEL-tiled: pixel p in [0,12544), slot = p + p/112.
// Conv block (448 thr = 7 waves): stages ALL weights (73.7KB) + one ci-half
// B window (64KB, 1024 slots) in LDS; k-loop = pure {ds_read A, ds_read B,
// MFMA}. Wave = 64co x 112px (7 frags, acc[7][4]).
// LDS B tile is CHUNK-SWIZZLED: within each 64B slot the four 16B chunks are
// permuted by chunk^=((slot>>1)&3), spreading B-read bank starts over all 8
// 4-bank windows (was an 8-way conflict = 4 extra cyc/read, r13/r14 PMC).
#define HW   112
#define HW2  12544
#define CH   64
#define NB   32
#define PRW  113
#define NP   12655          // interior slots per sample
#define POFF 128
#define PS   13056          // slots per half-plane per sample
#define NPC  (NB*HW2)
#define TPX  784            // pixels per conv tile (= 7 rows)

using u16 = unsigned short;
typedef __attribute__((ext_vector_type(8))) short bf16x8;   // 8 bf16 = 4 VGPRs
typedef __attribute__((ext_vector_type(4))) float f32x4;

__device__ __forceinline__ float b2f(u16 u) {
    union { unsigned int i; float f; } c;
    c.i = ((unsigned int)u) << 16;
    return c.f;
}
__device__ __forceinline__ u16 f2b(float f) {
    union { float f; unsigned int i; } c;
    c.f = f;
    unsigned int x = c.i;
    x += 0x7fffu + ((x >> 16) & 1u);   // RNE
    return (u16)(x >> 16);
}

// MODE 0: conv1 (input = padded x half-planes, output = padded y1 half-planes)
// MODE 1: conv2 (input = padded y1 half-planes with BN1 affine+ReLU applied
//                during staging; output = COMPACT y2 [b][pix12544][64])
// wt: bf16 [b][half][tap][kq][co][8ci] (73728 B / sample, matches LDS layout).
template<int MODE>
__global__ __launch_bounds__(448, 2)
void conv_mfma(const u16* __restrict__ img, const u16* __restrict__ wt,
               u16* __restrict__ outp, float* __restrict__ sums,
               const float* __restrict__ psums, const float* __restrict__ gamma,
               const float* __restrict__ beta)
{
    __shared__ u16 wl[36864];            // 73728 B weights, both halves
    __shared__ u16 bt[32768];            // 65536 B: 1024 slots x 32ci (one half)
    // XCD swizzle: 512 = 8 x 64 -> each XCD gets 4 whole samples.
    const int bid = (int)blockIdx.x;
    const int sid = (bid & 7) * 64 + (bid >> 3);
    const int b = sid >> 4, tile = sid & 15;
    const int p0 = tile * TPX;           // first pixel of tile
    const int w0 = tile * 791 - 114;     // staged window start (slot space)
    const int tid = threadIdx.x;
    const int lane = tid & 63, wave = tid >> 6;   // wave 0..6
    const int px = lane & 15, kg = lane >> 4;

    // ---- stage ALL weights: straight linear copy ----
    const u16* wtb = wt + (size_t)b * 36864;
    for (int c = tid; c < 4608; c += 448)
        *(bf16x8*)(wl + c * 8) = *(const bf16x8*)(wtb + c * 8);

    // ---- BN1 params for MODE1 staging (q = tid&3 loop-invariant: 448%4==0) ----
    float sc0[8], bi0[8], sc1[8], bi1[8];
    if (MODE == 1) {
        const int q = tid & 3;
#pragma unroll
        for (int e = 0; e < 8; ++e) {
            int c0 = q * 8 + e, c1 = 32 + q * 8 + e;
            float m0 = psums[c0] * (1.f / NPC), m1 = psums[c1] * (1.f / NPC);
            float v0 = psums[64 + c0] * (1.f / NPC) - m0 * m0;
            float v1 = psums[64 + c1] * (1.f / NPC) - m1 * m1;
            sc0[e] = gamma[c0] * rsqrtf(v0 + 1e-5f); bi0[e] = beta[c0] - m0 * sc0[e];
            sc1[e] = gamma[c1] * rsqrtf(v1 + 1e-5f); bi1[e] = beta[c1] - m1 * sc1[e];
        }
    }

    // ---- stage B half 0 (chunk-swizzled write; MODE1: affine+ReLU fused) ----
    {
        const u16* bp = img + ((size_t)(b * 2 + 0) * PS + POFF + w0) * 32;
        for (int c = tid; c < 4096; c += 448) {
            bf16x8 v = *(const bf16x8*)(bp + c * 8);
            if (MODE == 1) {
                int pt = w0 + (c >> 2);
                bool val = ((unsigned)pt < (unsigned)NP) && (pt % PRW != PRW - 1);
#pragma unroll
                for (int e = 0; e < 8; ++e) {
                    float t = b2f((u16)v[e]) * sc0[e] + bi0[e];
                    t = (val && t > 0.f) ? t : 0.f;
                    v[e] = (short)f2b(t);
                }
            }
            *(bf16x8*)(bt + (c >> 2) * 32 + (((c ^ (c >> 3)) & 3) << 3)) = v;
        }
    }
    __syncthreads();

    // ---- per-fragment LDS slot bases (pixel -> slot, incl. row-border skips) ----
    int lsf[7];
#pragma unroll
    for (int f = 0; f < 7; ++f) {
        const int pix = p0 + (wave * 7 + f) * 16 + px;
        lsf[f] = pix + pix / HW - w0;    // in [114, 903]; +-114 stays in [0,1023]
    }

    f32x4 acc[7][4];
#pragma unroll
    for (int f = 0; f < 7; ++f)
#pragma unroll
        for (int m = 0; m < 4; ++m) acc[f][m] = (f32x4)0.f;

    // ---- main loop: 2 ci-halves x 9 taps; pure LDS + MFMA ----
#pragma unroll
    for (int h = 0; h < 2; ++h) {
        if (h == 1) {
            __syncthreads();             // all waves done with half-0 B tile
            const u16* bp = img + ((size_t)(b * 2 + 1) * PS + POFF + w0) * 32;
            for (int c = tid; c < 4096; c += 448) {
                bf16x8 v = *(const bf16x8*)(bp + c * 8);
                if (MODE == 1) {
                    int pt = w0 + (c >> 2);
                    bool val = ((unsigned)pt < (unsigned)NP) && (pt % PRW != PRW - 1);
#pragma unroll
                    for (int e = 0; e < 8; ++e) {
                        float t = b2f((u16)v[e]) * sc1[e] + bi1[e];
                        t = (val && t > 0.f) ? t : 0.f;
                        v[e] = (short)f2b(t);
                    }
                }
                *(bf16x8*)(bt + (c >> 2) * 32 + (((c ^ (c >> 3)) & 3) << 3)) = v;
            }
            __syncthreads();
        }
#pragma unroll
        for (int tap = 0; tap < 9; ++tap) {
            const int off = (tap / 3 - 1) * PRW + (tap % 3 - 1);
            bf16x8 Af[4];
#pragma unroll
            for (int m = 0; m < 4; ++m)
                Af[m] = *(const bf16x8*)(wl + h * 18432 + tap * 2048 + kg * 512 + (m * 16 + px) * 8);
#pragma unroll
            for (int f = 0; f < 7; ++f) {
                const int s = lsf[f] + off;
                bf16x8 Bf = *(const bf16x8*)(bt + (s << 5) + (((kg ^ (s >> 1)) & 3) << 3));
#pragma unroll
                for (int m = 0; m < 4; ++m)
                    acc[f][m] = __builtin_amdgcn_mfma_f32_16x16x32_bf16(Af[m], Bf, acc[f][m], 0, 0, 0);
            }
        }
    }

    // ---- epilogue: unpredicated stores + fused BN batch-stat partials ----
    float s_[4][4], sq[4][4];
#pragma unroll
    for (int m = 0; m < 4; ++m)
#pragma unroll
        for (int q = 0; q < 4; ++q) { s_[m][q] = 0.f; sq[m][q] = 0.f; }

#pragma unroll
    for (int f = 0; f < 7; ++f) {
        const int pix  = p0 + (wave * 7 + f) * 16 + px;
        const int slot = pix + pix / HW;
#pragma unroll
        for (int m = 0; m < 4; ++m) {
            float v0 = acc[f][m][0], v1 = acc[f][m][1], v2 = acc[f][m][2], v3 = acc[f][m][3];
            s_[m][0] += v0; s_[m][1] += v1; s_[m][2] += v2; s_[m][3] += v3;
            sq[m][0] += v0 * v0; sq[m][1] += v1 * v1;
            sq[m][2] += v2 * v2; sq[m][3] += v3 * v3;
            uint2 pk;
            pk.x = ((unsigned)f2b(v1) << 16) | f2b(v0);
            pk.y = ((unsigned)f2b(v3) << 16) | f2b(v2);
            if (MODE == 0) {
                // y1 half-planes: half = m>>1, within-half co = (m&1)*16+kg*4
                u16* dst = outp + ((size_t)(b * 2 + (m >> 1)) * PS + POFF + slot) * 32
                                + (m & 1) * 16 + kg * 4;
                *(uint2*)dst = pk;
            } else {
                // compact y2 [b][pix][64]
                u16* dst = outp + ((size_t)b * HW2 + pix) * 64 + m * 16 + kg * 4;
                *(uint2*)dst = pk;
            }
        }
    }
#pragma unroll
    for (int off = 1; off < 16; off <<= 1) {
#pragma unroll
        for (int m = 0; m < 4; ++m)
#pragma unroll
            for (int q = 0; q < 4; ++q) {
                s_[m][q] += __shfl_xor(s_[m][q], off);
                sq[m][q] += __shfl_xor(sq[m][q], off);
            }
    }
    __syncthreads();                     // bt reads done; reuse as reduce buffer
    float* red = (float*)bt;             // 7 waves x 128 floats
    if (px == 0) {
#pragma unroll
        for (int m = 0; m < 4; ++m)
#pragma unroll
            for (int q = 0; q < 4; ++q) {
                int c = m * 16 + kg * 4 + q;
                red[wave * 128 + c]      = s_[m][q];
                red[wave * 128 + 64 + c] = sq[m][q];
            }
    }
    __syncthreads();
    if (tid < 128) {
        float t = 0.f;
#pragma unroll
        for (int k = 0; k < 7; ++k) t += red[k * 128 + tid];
        atomicAdd(&sums[tid], t);
    }
}

// x f32 NCHW -> padded bf16 half-plane image (interior only)
__global__ __launch_bounds__(256)
void xpad_kernel(const float* __restrict__ x, u16* __restrict__ img)
{
    const int b  = blockIdx.y;
    const int y  = blockIdx.x * 2 + (threadIdx.x >> 7);
    const int px = threadIdx.x & 127;
    if (px >= HW) return;
    const float* xr = x + (size_t)b * CH * HW2 + (size_t)y * HW + px;
#pragma unroll
    for (int cg = 0; cg < 8; ++cg) {
        bf16x8 pk;
#pragma unroll
        for (int j = 0; j < 8; ++j)
            pk[j] = (short)f2b(xr[(size_t)(cg * 8 + j) * HW2]);
        u16* op = img + ((size_t)(b * 2 + (cg >> 2)) * PS + POFF + (size_t)y * PRW + px) * 32
                      + (cg & 3) * 8;
        *(bf16x8*)op = pk;
    }
}

// zero pad slots (512 per half-plane per sample, both images) + stats area
__global__ void border_kernel(u16* __restrict__ a, u16* __restrict__ y1,
                              float* __restrict__ st)
{
    if (blockIdx.x == 256) {
        if (threadIdx.x < 256) st[threadIdx.x] = 0.f;
        return;
    }
    int t = blockIdx.x * 256 + threadIdx.x;      // 0..65535
    u16* buf = (t >= 32768) ? y1 : a;
    int t2 = t & 32767;
    int bh = t2 >> 9;                            // b*2+h (0..63)
    int s  = t2 & 511;
    int slot;
    if (s < POFF)            slot = s;                                   // leading 128
    else if (s < POFF + 273) slot = POFF + NP + (s - POFF);              // trailing 273
    else                     slot = POFF + (s - (POFF + 273)) * PRW + (PRW - 1); // 111 borders
    float4* q = (float4*)(buf + ((size_t)bh * PS + slot) * 32);
#pragma unroll
    for (int i = 0; i < 4; ++i) q[i] = (float4){0.f, 0.f, 0.f, 0.f};
}

// both weights: [b][co][ci][3][3] f32 -> [b][half][tap][kq][co][8ci] bf16
__global__ __launch_bounds__(256)
void repack2_kernel(const float* __restrict__ w1, const float* __restrict__ w2,
                    u16* __restrict__ wt1, u16* __restrict__ wt2)
{
    int i = blockIdx.x * 256 + threadIdx.x;      // 0..2359295
    const int N = NB * 36864;
    const float* w = (i < N) ? w1 : w2;
    u16* wt = (i < N) ? wt1 : wt2;
    int o = (i < N) ? i : i - N;
    int b = o / 36864, r = o - b * 36864;
    int half = r / 18432; r -= half * 18432;
    int tap  = r / 2048;  r -= tap * 2048;
    int kq   = r / 512;   r -= kq * 512;
    int co   = r / 8;
    int ci   = half * 32 + kq * 8 + (r & 7);
    wt[o] = f2b(w[(((size_t)b * 64 + co) * 64 + ci) * 9 + tap]);
}

// out = relu(bn2(y2) + x), NCHW f32 via LDS transpose; y2 compact [b][pix][64]
__global__ __launch_bounds__(256)
void finalize_kernel(const u16* __restrict__ y2, const float* __restrict__ sums,
                     const float* __restrict__ gamma, const float* __restrict__ beta,
                     const float* __restrict__ x, float* __restrict__ out)
{
    __shared__ float lt[64][116];
    __shared__ float sbl[128];
    const int b = blockIdx.y, y = blockIdx.x;
    const int tid = threadIdx.x;
    if (tid < 64) {
        float mean = sums[tid] * (1.f / NPC);
        float var  = sums[64 + tid] * (1.f / NPC) - mean * mean;
        float sc   = gamma[tid] * rsqrtf(var + 1e-5f);
        sbl[tid]      = sc;
        sbl[64 + tid] = beta[tid] - mean * sc;
    }
    __syncthreads();
    const u16* rowp = y2 + ((size_t)b * HW2 + (size_t)y * HW) * 64;
    {
        const int cg = tid & 7;
        float sc[8], bi[8];
#pragma unroll
        for (int e = 0; e < 8; ++e) { sc[e] = sbl[cg * 8 + e]; bi[e] = sbl[64 + cg * 8 + e]; }
        for (int t = tid; t < HW * 8; t += 256) {
            int px = t >> 3;
            bf16x8 v = *(const bf16x8*)(rowp + px * 64 + cg * 8);
#pragma unroll
            for (int e = 0; e < 8; ++e)
                lt[cg * 8 + e][px] = b2f((u16)v[e]) * sc[e] + bi[e];
        }
    }
    __syncthreads();
    {
        const int c = tid >> 2, xg = (tid & 3) * 28;
        size_t base = ((size_t)b * CH + c) * HW2 + (size_t)y * HW + xg;
#pragma unroll
        for (int i = 0; i < 7; ++i) {
            float4 xv = *(const float4*)(x + base + i * 4);
            float4 r;
            r.x = fmaxf(lt[c][xg + i * 4 + 0] + xv.x, 0.f);
            r.y = fmaxf(lt[c][xg + i * 4 + 1] + xv.y, 0.f);
            r.z = fmaxf(lt[c][xg + i * 4 + 2] + xv.z, 0.f);
            r.w = fmaxf(lt[c][xg + i * 4 + 3] + xv.w, 0.f);
            *(float4*)(out + base + i * 4) = r;
        }
    }
}

extern "C" void kernel_launch(void* const* d_in, const int* in_sizes, int n_in,
                              void* d_out, int out_size, void* d_ws, size_t ws_size,
                              hipStream_t stream)
{
    const float* x  = (const float*)d_in[0];
    const float* w1 = (const float*)d_in[1];
    const float* w2 = (const float*)d_in[2];
    const float* g1 = (const float*)d_in[3];
    const float* b1 = (const float*)d_in[4];
    const float* g2 = (const float*)d_in[5];
    const float* b2 = (const float*)d_in[6];
    float* out = (float*)d_out;

    // ws: imgA (padded x, 53.5MB) at 0; y2 compact (51.4MB) OVERLAPS imgA
    // (imgA dead after conv1); stats at +56MB.
    char* ws = (char*)d_ws;
    u16*   imgA = (u16*)ws;
    u16*   y2c  = (u16*)ws;
    float* st   = (float*)(ws + (size_t)(56u << 20));
    float* sums1 = st, *sums2 = st + 128;
    // d_out hosts y1 half-planes + repacked weights; dead before finalize writes.
    char*  oc   = (char*)d_out;
    u16*   y1p  = (u16*)oc;                            // 53.5 MB
    u16*   wt1  = (u16*)(oc + (size_t)(54u << 20));    // 2.25 MB
    u16*   wt2  = (u16*)(oc + (size_t)(58u << 20));    // 2.25 MB

    border_kernel<<<257, 256, 0, stream>>>(imgA, y1p, st);
    xpad_kernel<<<dim3(56, 32), 256, 0, stream>>>(x, imgA);
    repack2_kernel<<<9216, 256, 0, stream>>>(w1, w2, wt1, wt2);

    conv_mfma<0><<<512, 448, 0, stream>>>(imgA, wt1, y1p, sums1, st, g1, b1);
    conv_mfma<1><<<512, 448, 0, stream>>>(y1p, wt2, y2c, sums2, sums1, g1, b1);
    finalize_kernel<<<dim3(112, 32), 256, 0, stream>>>(y2c, sums2, g2, b2, x, out);
}

// Round 16
// 208.329 us; speedup vs baseline: 1.1375x; 1.1375x over previous
//
#include <hip/hip_runtime.h>

// B=32, C=64, H=W=112. Per-sample 3x3 convs via bf16 MFMA implicit GEMM.
// Image format: per-sample ZERO-PADDED half-planes [b][half(ci32)][slot][32ci],
// slot = POFF + y*113 + x; col 112 of each row = shared zero border; 128 zero
// slots lead, 273 trail. PIXEL-tiled: pixel p in [0,12544), slot = p + p/112.
// Conv block (448 thr = 7 waves): stages ALL weights (73.7KB) + one ci-half
// B window (64KB, 1024 slots, LINEAR layout) in LDS; k-loop = pure
// {ds_read A, ds_read B, MFMA}. Wave = 64co x 112px (7 frags, acc[7][4]).
// r16: staging via __builtin_amdgcn_global_load_lds width=16 (W both convs,
// B conv1) — no VGPR round-trip, no staging VALU; drained by the barrier's
// vmcnt(0). Conv2's B keeps the register path (BN1 affine+ReLU fused).
#define HW   112
#define HW2  12544
#define CH   64
#define NB   32
#define PRW  113
#define NP   12655          // interior slots per sample
#define POFF 128
#define PS   13056          // slots per half-plane per sample
#define NPC  (NB*HW2)
#define TPX  784            // pixels per conv tile (= 7 rows)

using u16 = unsigned short;
typedef __attribute__((ext_vector_type(8))) short bf16x8;   // 8 bf16 = 4 VGPRs
typedef __attribute__((ext_vector_type(4))) float f32x4;

__device__ __forceinline__ float b2f(u16 u) {
    union { unsigned int i; float f; } c;
    c.i = ((unsigned int)u) << 16;
    return c.f;
}
__device__ __forceinline__ u16 f2b(float f) {
    union { float f; unsigned int i; } c;
    c.f = f;
    unsigned int x = c.i;
    x += 0x7fffu + ((x >> 16) & 1u);   // RNE
    return (u16)(x >> 16);
}

// async global->LDS, 16B per lane; l must be the WAVE-UNIFORM base
// (HW dest = base + lane*16). Drained by __syncthreads' vmcnt(0).
__device__ __forceinline__ void gl2lds(const u16* g, u16* l) {
    __builtin_amdgcn_global_load_lds(
        (const __attribute__((address_space(1))) unsigned int*)g,
        (__attribute__((address_space(3))) unsigned int*)l, 16, 0, 0);
}

// MODE 0: conv1 (input = padded x half-planes, output = padded y1 half-planes)
// MODE 1: conv2 (input = padded y1 half-planes with BN1 affine+ReLU applied
//                during staging; output = COMPACT y2 [b][pix12544][64])
// wt: bf16 [b][half][tap][kq][co][8ci] (73728 B / sample, matches LDS layout).
template<int MODE>
__global__ __launch_bounds__(448, 2)
void conv_mfma(const u16* __restrict__ img, const u16* __restrict__ wt,
               u16* __restrict__ outp, float* __restrict__ sums,
               const float* __restrict__ psums, const float* __restrict__ gamma,
               const float* __restrict__ beta)
{
    __shared__ u16 wl[36864];            // 73728 B weights, both halves
    __shared__ u16 bt[32768];            // 65536 B: 1024 slots x 32ci (one half)
    // XCD swizzle: 512 = 8 x 64 -> each XCD gets 4 whole samples.
    const int bid = (int)blockIdx.x;
    const int sid = (bid & 7) * 64 + (bid >> 3);
    const int b = sid >> 4, tile = sid & 15;
    const int p0 = tile * TPX;           // first pixel of tile
    const int w0 = tile * 791 - 114;     // staged window start (slot space)
    const int tid = threadIdx.x;
    const int lane = tid & 63, wave = tid >> 6;   // wave 0..6
    const int px = lane & 15, kg = lane >> 4;
    const u16* wtb = wt + (size_t)b * 36864;

    // ---- stage ALL weights: async gllds, waves 0-5, 12 chunks each ----
    if (tid < 384) {
#pragma unroll
        for (int i = 0; i < 12; ++i) {
            const int c = i * 384 + tid;                 // 4608 chunks exact
            gl2lds(wtb + (size_t)c * 8, wl + (size_t)(c - lane) * 8);
        }
    }

    // ---- BN1 params for MODE1 staging (q = tid&3 loop-invariant: 448%4==0) ----
    float sc0[8], bi0[8], sc1[8], bi1[8];
    if (MODE == 1) {
        const int q = tid & 3;
#pragma unroll
        for (int e = 0; e < 8; ++e) {
            int c0 = q * 8 + e, c1 = 32 + q * 8 + e;
            float m0 = psums[c0] * (1.f / NPC), m1 = psums[c1] * (1.f / NPC);
            float v0 = psums[64 + c0] * (1.f / NPC) - m0 * m0;
            float v1 = psums[64 + c1] * (1.f / NPC) - m1 * m1;
            sc0[e] = gamma[c0] * rsqrtf(v0 + 1e-5f); bi0[e] = beta[c0] - m0 * sc0[e];
            sc1[e] = gamma[c1] * rsqrtf(v1 + 1e-5f); bi1[e] = beta[c1] - m1 * sc1[e];
        }
    }

    // ---- stage B half 0 (MODE0: async gllds; MODE1: affine+ReLU register path) ----
    {
        const u16* bp = img + ((size_t)(b * 2 + 0) * PS + POFF + w0) * 32;
        if (MODE == 0) {
#pragma unroll
            for (int i = 0; i < 9; ++i) {
                const int c = i * 448 + tid;             // 4032 chunks
                gl2lds(bp + (size_t)c * 8, bt + (size_t)(c - lane) * 8);
            }
            if (wave == 6)                               // remaining 64 chunks
                gl2lds(bp + (size_t)(4032 + lane) * 8, bt + (size_t)4032 * 8);
        } else {
            for (int c = tid; c < 4096; c += 448) {
                bf16x8 v = *(const bf16x8*)(bp + c * 8);
                int pt = w0 + (c >> 2);
                bool val = ((unsigned)pt < (unsigned)NP) && (pt % PRW != PRW - 1);
#pragma unroll
                for (int e = 0; e < 8; ++e) {
                    float t = b2f((u16)v[e]) * sc0[e] + bi0[e];
                    t = (val && t > 0.f) ? t : 0.f;
                    v[e] = (short)f2b(t);
                }
                *(bf16x8*)(bt + c * 8) = v;
            }
        }
    }
    __syncthreads();

    // ---- per-fragment LDS slot bases (pixel -> slot, incl. row-border skips) ----
    int lsf[7];
#pragma unroll
    for (int f = 0; f < 7; ++f) {
        const int pix = p0 + (wave * 7 + f) * 16 + px;
        lsf[f] = pix + pix / HW - w0;    // in [114, 903]; +-114 stays in [0,1023]
    }

    f32x4 acc[7][4];
#pragma unroll
    for (int f = 0; f < 7; ++f)
#pragma unroll
        for (int m = 0; m < 4; ++m) acc[f][m] = (f32x4)0.f;

    // ---- main loop: 2 ci-halves x 9 taps; pure LDS + MFMA ----
#pragma unroll
    for (int h = 0; h < 2; ++h) {
        if (h == 1) {
            __syncthreads();             // all waves done with half-0 B tile
            const u16* bp = img + ((size_t)(b * 2 + 1) * PS + POFF + w0) * 32;
            if (MODE == 0) {
#pragma unroll
                for (int i = 0; i < 9; ++i) {
                    const int c = i * 448 + tid;
                    gl2lds(bp + (size_t)c * 8, bt + (size_t)(c - lane) * 8);
                }
                if (wave == 6)
                    gl2lds(bp + (size_t)(4032 + lane) * 8, bt + (size_t)4032 * 8);
            } else {
                for (int c = tid; c < 4096; c += 448) {
                    bf16x8 v = *(const bf16x8*)(bp + c * 8);
                    int pt = w0 + (c >> 2);
                    bool val = ((unsigned)pt < (unsigned)NP) && (pt % PRW != PRW - 1);
#pragma unroll
                    for (int e = 0; e < 8; ++e) {
                        float t = b2f((u16)v[e]) * sc1[e] + bi1[e];
                        t = (val && t > 0.f) ? t : 0.f;
                        v[e] = (short)f2b(t);
                    }
                    *(bf16x8*)(bt + c * 8) = v;
                }
            }
            __syncthreads();
        }
#pragma unroll
        for (int tap = 0; tap < 9; ++tap) {
            const int off = (tap / 3 - 1) * PRW + (tap % 3 - 1);
            bf16x8 Af[4];
#pragma unroll
            for (int m = 0; m < 4; ++m)
                Af[m] = *(const bf16x8*)(wl + h * 18432 + tap * 2048 + kg * 512 + (m * 16 + px) * 8);
#pragma unroll
            for (int f = 0; f < 7; ++f) {
                bf16x8 Bf = *(const bf16x8*)(bt + (lsf[f] + off) * 32 + kg * 8);
#pragma unroll
                for (int m = 0; m < 4; ++m)
                    acc[f][m] = __builtin_amdgcn_mfma_f32_16x16x32_bf16(Af[m], Bf, acc[f][m], 0, 0, 0);
            }
        }
    }

    // ---- epilogue: unpredicated stores + fused BN batch-stat partials ----
    float s_[4][4], sq[4][4];
#pragma unroll
    for (int m = 0; m < 4; ++m)
#pragma unroll
        for (int q = 0; q < 4; ++q) { s_[m][q] = 0.f; sq[m][q] = 0.f; }

#pragma unroll
    for (int f = 0; f < 7; ++f) {
        const int pix  = p0 + (wave * 7 + f) * 16 + px;
        const int slot = pix + pix / HW;
#pragma unroll
        for (int m = 0; m < 4; ++m) {
            float v0 = acc[f][m][0], v1 = acc[f][m][1], v2 = acc[f][m][2], v3 = acc[f][m][3];
            s_[m][0] += v0; s_[m][1] += v1; s_[m][2] += v2; s_[m][3] += v3;
            sq[m][0] += v0 * v0; sq[m][1] += v1 * v1;
            sq[m][2] += v2 * v2; sq[m][3] += v3 * v3;
            uint2 pk;
            pk.x = ((unsigned)f2b(v1) << 16) | f2b(v0);
            pk.y = ((unsigned)f2b(v3) << 16) | f2b(v2);
            if (MODE == 0) {
                // y1 half-planes: half = m>>1, within-half co = (m&1)*16+kg*4
                u16* dst = outp + ((size_t)(b * 2 + (m >> 1)) * PS + POFF + slot) * 32
                                + (m & 1) * 16 + kg * 4;
                *(uint2*)dst = pk;
            } else {
                // compact y2 [b][pix][64]
                u16* dst = outp + ((size_t)b * HW2 + pix) * 64 + m * 16 + kg * 4;
                *(uint2*)dst = pk;
            }
        }
    }
#pragma unroll
    for (int off = 1; off < 16; off <<= 1) {
#pragma unroll
        for (int m = 0; m < 4; ++m)
#pragma unroll
            for (int q = 0; q < 4; ++q) {
                s_[m][q] += __shfl_xor(s_[m][q], off);
                sq[m][q] += __shfl_xor(sq[m][q], off);
            }
    }
    __syncthreads();                     // bt reads done; reuse as reduce buffer
    float* red = (float*)bt;             // 7 waves x 128 floats
    if (px == 0) {
#pragma unroll
        for (int m = 0; m < 4; ++m)
#pragma unroll
            for (int q = 0; q < 4; ++q) {
                int c = m * 16 + kg * 4 + q;
                red[wave * 128 + c]      = s_[m][q];
                red[wave * 128 + 64 + c] = sq[m][q];
            }
    }
    __syncthreads();
    if (tid < 128) {
        float t = 0.f;
#pragma unroll
        for (int k = 0; k < 7; ++k) t += red[k * 128 + tid];
        atomicAdd(&sums[tid], t);
    }
}

// x f32 NCHW -> padded bf16 half-plane image (interior only)
__global__ __launch_bounds__(256)
void xpad_kernel(const float* __restrict__ x, u16* __restrict__ img)
{
    const int b  = blockIdx.y;
    const int y  = blockIdx.x * 2 + (threadIdx.x >> 7);
    const int px = threadIdx.x & 127;
    if (px >= HW) return;
    const float* xr = x + (size_t)b * CH * HW2 + (size_t)y * HW + px;
#pragma unroll
    for (int cg = 0; cg < 8; ++cg) {
        bf16x8 pk;
#pragma unroll
        for (int j = 0; j < 8; ++j)
            pk[j] = (short)f2b(xr[(size_t)(cg * 8 + j) * HW2]);
        u16* op = img + ((size_t)(b * 2 + (cg >> 2)) * PS + POFF + (size_t)y * PRW + px) * 32
                      + (cg & 3) * 8;
        *(bf16x8*)op = pk;
    }
}

// zero pad slots (512 per half-plane per sample, both images) + stats area
__global__ void border_kernel(u16* __restrict__ a, u16* __restrict__ y1,
                              float* __restrict__ st)
{
    if (blockIdx.x == 256) {
        if (threadIdx.x < 256) st[threadIdx.x] = 0.f;
        return;
    }
    int t = blockIdx.x * 256 + threadIdx.x;      // 0..65535
    u16* buf = (t >= 32768) ? y1 : a;
    int t2 = t & 32767;
    int bh = t2 >> 9;                            // b*2+h (0..63)
    int s  = t2 & 511;
    int slot;
    if (s < POFF)            slot = s;                                   // leading 128
    else if (s < POFF + 273) slot = POFF + NP + (s - POFF);              // trailing 273
    else                     slot = POFF + (s - (POFF + 273)) * PRW + (PRW - 1); // 111 borders
    float4* q = (float4*)(buf + ((size_t)bh * PS + slot) * 32);
#pragma unroll
    for (int i = 0; i < 4; ++i) q[i] = (float4){0.f, 0.f, 0.f, 0.f};
}

// both weights: [b][co][ci][3][3] f32 -> [b][half][tap][kq][co][8ci] bf16
__global__ __launch_bounds__(256)
void repack2_kernel(const float* __restrict__ w1, const float* __restrict__ w2,
                    u16* __restrict__ wt1, u16* __restrict__ wt2)
{
    int i = blockIdx.x * 256 + threadIdx.x;      // 0..2359295
    const int N = NB * 36864;
    const float* w = (i < N) ? w1 : w2;
    u16* wt = (i < N) ? wt1 : wt2;
    int o = (i < N) ? i : i - N;
    int b = o / 36864, r = o - b * 36864;
    int half = r / 18432; r -= half * 18432;
    int tap  = r / 2048;  r -= tap * 2048;
    int kq   = r / 512;   r -= kq * 512;
    int co   = r / 8;
    int ci   = half * 32 + kq * 8 + (r & 7);
    wt[o] = f2b(w[(((size_t)b * 64 + co) * 64 + ci) * 9 + tap]);
}

// out = relu(bn2(y2) + x), NCHW f32 via LDS transpose; y2 compact [b][pix][64]
__global__ __launch_bounds__(256)
void finalize_kernel(const u16* __restrict__ y2, const float* __restrict__ sums,
                     const float* __restrict__ gamma, const float* __restrict__ beta,
                     const float* __restrict__ x, float* __restrict__ out)
{
    __shared__ float lt[64][116];
    __shared__ float sbl[128];
    const int b = blockIdx.y, y = blockIdx.x;
    const int tid = threadIdx.x;
    if (tid < 64) {
        float mean = sums[tid] * (1.f / NPC);
        float var  = sums[64 + tid] * (1.f / NPC) - mean * mean;
        float sc   = gamma[tid] * rsqrtf(var + 1e-5f);
        sbl[tid]      = sc;
        sbl[64 + tid] = beta[tid] - mean * sc;
    }
    __syncthreads();
    const u16* rowp = y2 + ((size_t)b * HW2 + (size_t)y * HW) * 64;
    {
        const int cg = tid & 7;
        float sc[8], bi[8];
#pragma unroll
        for (int e = 0; e < 8; ++e) { sc[e] = sbl[cg * 8 + e]; bi[e] = sbl[64 + cg * 8 + e]; }
        for (int t = tid; t < HW * 8; t += 256) {
            int px = t >> 3;
            bf16x8 v = *(const bf16x8*)(rowp + px * 64 + cg * 8);
#pragma unroll
            for (int e = 0; e < 8; ++e)
                lt[cg * 8 + e][px] = b2f((u16)v[e]) * sc[e] + bi[e];
        }
    }
    __syncthreads();
    {
        const int c = tid >> 2, xg = (tid & 3) * 28;
        size_t base = ((size_t)b * CH + c) * HW2 + (size_t)y * HW + xg;
#pragma unroll
        for (int i = 0; i < 7; ++i) {
            float4 xv = *(const float4*)(x + base + i * 4);
            float4 r;
            r.x = fmaxf(lt[c][xg + i * 4 + 0] + xv.x, 0.f);
            r.y = fmaxf(lt[c][xg + i * 4 + 1] + xv.y, 0.f);
            r.z = fmaxf(lt[c][xg + i * 4 + 2] + xv.z, 0.f);
            r.w = fmaxf(lt[c][xg + i * 4 + 3] + xv.w, 0.f);
            *(float4*)(out + base + i * 4) = r;
        }
    }
}

extern "C" void kernel_launch(void* const* d_in, const int* in_sizes, int n_in,
                              void* d_out, int out_size, void* d_ws, size_t ws_size,
                              hipStream_t stream)
{
    const float* x  = (const float*)d_in[0];
    const float* w1 = (const float*)d_in[1];
    const float* w2 = (const float*)d_in[2];
    const float* g1 = (const float*)d_in[3];
    const float* b1 = (const float*)d_in[4];
    const float* g2 = (const float*)d_in[5];
    const float* b2 = (const float*)d_in[6];
    float* out = (float*)d_out;

    // ws: imgA (padded x, 53.5MB) at 0; y2 compact (51.4MB) OVERLAPS imgA
    // (imgA dead after conv1); stats at +56MB.
    char* ws = (char*)d_ws;
    u16*   imgA = (u16*)ws;
    u16*   y2c  = (u16*)ws;
    float* st   = (float*)(ws + (size_t)(56u << 20));
    float* sums1 = st, *sums2 = st + 128;
    // d_out hosts y1 half-planes + repacked weights; dead before finalize writes.
    char*  oc   = (char*)d_out;
    u16*   y1p  = (u16*)oc;                            // 53.5 MB
    u16*   wt1  = (u16*)(oc + (size_t)(54u << 20));    // 2.25 MB
    u16*   wt2  = (u16*)(oc + (size_t)(58u << 20));    // 2.25 MB

    border_kernel<<<257, 256, 0, stream>>>(imgA, y1p, st);
    xpad_kernel<<<dim3(56, 32), 256, 0, stream>>>(x, imgA);
    repack2_kernel<<<9216, 256, 0, stream>>>(w1, w2, wt1, wt2);

    conv_mfma<0><<<512, 448, 0, stream>>>(imgA, wt1, y1p, sums1, st, g1, b1);
    conv_mfma<1><<<512, 448, 0, stream>>>(y1p, wt2, y2c, sums2, sums1, g1, b1);
    finalize_kernel<<<dim3(112, 32), 256, 0, stream>>>(y2c, sums2, g2, b2, x, out);
}

// Round 17
// 191.867 us; speedup vs baseline: 1.2350x; 1.0858x over previous
//
#include <hip/hip_runtime.h>

// B=32, C=64, H=W=112. Per-sample 3x3 convs via bf16 MFMA implicit GEMM.
// r17: xpad + border kernels ELIMINATED. conv1 stages B directly from x (f32
// NCHW gather + f2b + zero-pad mask in registers); conv2 reads y1 half-planes
// [b][half(ci32)][slot][32ci], slot = POFF + y*113 + x (col 112 = zero border,
// masked during staging — y1p pad slots are never even written).
// Conv block (448 thr = 7 waves): W staged via global_load_lds (73.7KB), one
// ci-half B window (64KB, 1024 slots) in LDS; k-loop = pure {ds_read A,
// ds_read B, MFMA}. Wave = 64co x 112px (7 frags, acc[7][4]).
// Pipeline: repack2(+stats zero) -> conv1 -> conv2 -> finalize. 4 launches.
#define HW   112
#define HW2  12544
#define CH   64
#define NB   32
#define PRW  113
#define NP   12655          // interior slots per sample
#define POFF 128
#define PS   13056          // slots per half-plane per sample
#define NPC  (NB*HW2)
#define TPX  784            // pixels per conv tile (= 7 rows)

using u16 = unsigned short;
typedef __attribute__((ext_vector_type(8))) short bf16x8;   // 8 bf16 = 4 VGPRs
typedef __attribute__((ext_vector_type(4))) float f32x4;

__device__ __forceinline__ float b2f(u16 u) {
    union { unsigned int i; float f; } c;
    c.i = ((unsigned int)u) << 16;
    return c.f;
}
__device__ __forceinline__ u16 f2b(float f) {
    union { float f; unsigned int i; } c;
    c.f = f;
    unsigned int x = c.i;
    x += 0x7fffu + ((x >> 16) & 1u);   // RNE
    return (u16)(x >> 16);
}

// async global->LDS, 16B per lane; l must be the WAVE-UNIFORM base
// (HW dest = base + lane*16). Drained by __syncthreads' vmcnt(0).
__device__ __forceinline__ void gl2lds(const u16* g, u16* l) {
    __builtin_amdgcn_global_load_lds(
        (const __attribute__((address_space(1))) unsigned int*)g,
        (__attribute__((address_space(3))) unsigned int*)l, 16, 0, 0);
}

// MODE 0: conv1 (input = x f32 NCHW, transpose+pad+convert fused into staging;
//                output = y1 half-planes, interior slots only)
// MODE 1: conv2 (input = y1 half-planes with BN1 affine+ReLU applied during
//                staging, pad slots masked to 0; output = COMPACT y2 [b][pix][64])
// wt: bf16 [b][half][tap][kq][co][8ci] (73728 B / sample, matches LDS layout).
template<int MODE>
__global__ __launch_bounds__(448, 2)
void conv_mfma(const float* __restrict__ xf, const u16* __restrict__ img,
               const u16* __restrict__ wt,
               u16* __restrict__ outp, float* __restrict__ sums,
               const float* __restrict__ psums, const float* __restrict__ gamma,
               const float* __restrict__ beta)
{
    __shared__ u16 wl[36864];            // 73728 B weights, both halves
    __shared__ u16 bt[32768];            // 65536 B: 1024 slots x 32ci (one half)
    // XCD swizzle: 512 = 8 x 64 -> each XCD gets 4 whole samples.
    const int bid = (int)blockIdx.x;
    const int sid = (bid & 7) * 64 + (bid >> 3);
    const int b = sid >> 4, tile = sid & 15;
    const int p0 = tile * TPX;           // first pixel of tile
    const int w0 = tile * 791 - 114;     // staged window start (slot space)
    const int tid = threadIdx.x;
    const int lane = tid & 63, wave = tid >> 6;   // wave 0..6
    const int px = lane & 15, kg = lane >> 4;
    const u16* wtb = wt + (size_t)b * 36864;

    // ---- stage ALL weights: async gllds, waves 0-5, 12 chunks each ----
    if (tid < 384) {
#pragma unroll
        for (int i = 0; i < 12; ++i) {
            const int c = i * 384 + tid;                 // 4608 chunks exact
            gl2lds(wtb + (size_t)c * 8, wl + (size_t)(c - lane) * 8);
        }
    }

    // ---- BN1 params for MODE1 staging (q = tid&3 loop-invariant: 448%4==0) ----
    float sc0[8], bi0[8], sc1[8], bi1[8];
    if (MODE == 1) {
        const int q = tid & 3;
#pragma unroll
        for (int e = 0; e < 8; ++e) {
            int c0 = q * 8 + e, c1 = 32 + q * 8 + e;
            float m0 = psums[c0] * (1.f / NPC), m1 = psums[c1] * (1.f / NPC);
            float v0 = psums[64 + c0] * (1.f / NPC) - m0 * m0;
            float v1 = psums[64 + c1] * (1.f / NPC) - m1 * m1;
            sc0[e] = gamma[c0] * rsqrtf(v0 + 1e-5f); bi0[e] = beta[c0] - m0 * sc0[e];
            sc1[e] = gamma[c1] * rsqrtf(v1 + 1e-5f); bi1[e] = beta[c1] - m1 * sc1[e];
        }
    }
    const float* xb = (MODE == 0) ? xf + (size_t)b * CH * HW2 : nullptr;

    // ---- stage B half 0 ----
    // MODE0: gather from x f32 (transpose+convert+pad fused).
    // MODE1: y1 bf16 + BN1 affine+ReLU, pads masked.
    {
        const u16* bp = img + ((size_t)(b * 2 + 0) * PS + POFF + w0) * 32;
        for (int c = tid; c < 4096; c += 448) {
            const int pt = w0 + (c >> 2);
            bf16x8 v = (bf16x8)0;
            if (MODE == 0) {
                if ((unsigned)pt < (unsigned)NP) {
                    int y  = (unsigned)pt / PRW;
                    int xc = pt - y * PRW;
                    if (xc != PRW - 1) {
                        const float* src = xb + (size_t)((c & 3) * 8) * HW2 + y * HW + xc;
#pragma unroll
                        for (int e = 0; e < 8; ++e)
                            v[e] = (short)f2b(src[(size_t)e * HW2]);
                    }
                }
            } else {
                bool val = ((unsigned)pt < (unsigned)NP) && (pt % PRW != PRW - 1);
                bf16x8 r = *(const bf16x8*)(bp + c * 8);
#pragma unroll
                for (int e = 0; e < 8; ++e) {
                    float t = b2f((u16)r[e]) * sc0[e] + bi0[e];
                    t = (val && t > 0.f) ? t : 0.f;
                    v[e] = (short)f2b(t);
                }
            }
            *(bf16x8*)(bt + c * 8) = v;
        }
    }
    __syncthreads();

    // ---- per-fragment LDS slot bases (pixel -> slot, incl. row-border skips) ----
    int lsf[7];
#pragma unroll
    for (int f = 0; f < 7; ++f) {
        const int pix = p0 + (wave * 7 + f) * 16 + px;
        lsf[f] = pix + pix / HW - w0;    // in [114, 903]; +-114 stays in [0,1023]
    }

    f32x4 acc[7][4];
#pragma unroll
    for (int f = 0; f < 7; ++f)
#pragma unroll
        for (int m = 0; m < 4; ++m) acc[f][m] = (f32x4)0.f;

    // ---- main loop: 2 ci-halves x 9 taps; pure LDS + MFMA ----
#pragma unroll
    for (int h = 0; h < 2; ++h) {
        if (h == 1) {
            __syncthreads();             // all waves done with half-0 B tile
            const u16* bp = img + ((size_t)(b * 2 + 1) * PS + POFF + w0) * 32;
            for (int c = tid; c < 4096; c += 448) {
                const int pt = w0 + (c >> 2);
                bf16x8 v = (bf16x8)0;
                if (MODE == 0) {
                    if ((unsigned)pt < (unsigned)NP) {
                        int y  = (unsigned)pt / PRW;
                        int xc = pt - y * PRW;
                        if (xc != PRW - 1) {
                            const float* src = xb + (size_t)(32 + (c & 3) * 8) * HW2 + y * HW + xc;
#pragma unroll
                            for (int e = 0; e < 8; ++e)
                                v[e] = (short)f2b(src[(size_t)e * HW2]);
                        }
                    }
                } else {
                    bool val = ((unsigned)pt < (unsigned)NP) && (pt % PRW != PRW - 1);
                    bf16x8 r = *(const bf16x8*)(bp + c * 8);
#pragma unroll
                    for (int e = 0; e < 8; ++e) {
                        float t = b2f((u16)r[e]) * sc1[e] + bi1[e];
                        t = (val && t > 0.f) ? t : 0.f;
                        v[e] = (short)f2b(t);
                    }
                }
                *(bf16x8*)(bt + c * 8) = v;
            }
            __syncthreads();
        }
#pragma unroll
        for (int tap = 0; tap < 9; ++tap) {
            const int off = (tap / 3 - 1) * PRW + (tap % 3 - 1);
            bf16x8 Af[4];
#pragma unroll
            for (int m = 0; m < 4; ++m)
                Af[m] = *(const bf16x8*)(wl + h * 18432 + tap * 2048 + kg * 512 + (m * 16 + px) * 8);
#pragma unroll
            for (int f = 0; f < 7; ++f) {
                bf16x8 Bf = *(const bf16x8*)(bt + (lsf[f] + off) * 32 + kg * 8);
#pragma unroll
                for (int m = 0; m < 4; ++m)
                    acc[f][m] = __builtin_amdgcn_mfma_f32_16x16x32_bf16(Af[m], Bf, acc[f][m], 0, 0, 0);
            }
        }
    }

    // ---- epilogue: unpredicated stores + fused BN batch-stat partials ----
    float s_[4][4], sq[4][4];
#pragma unroll
    for (int m = 0; m < 4; ++m)
#pragma unroll
        for (int q = 0; q < 4; ++q) { s_[m][q] = 0.f; sq[m][q] = 0.f; }

#pragma unroll
    for (int f = 0; f < 7; ++f) {
        const int pix  = p0 + (wave * 7 + f) * 16 + px;
        const int slot = pix + pix / HW;
#pragma unroll
        for (int m = 0; m < 4; ++m) {
            float v0 = acc[f][m][0], v1 = acc[f][m][1], v2 = acc[f][m][2], v3 = acc[f][m][3];
            s_[m][0] += v0; s_[m][1] += v1; s_[m][2] += v2; s_[m][3] += v3;
            sq[m][0] += v0 * v0; sq[m][1] += v1 * v1;
            sq[m][2] += v2 * v2; sq[m][3] += v3 * v3;
            uint2 pk;
            pk.x = ((unsigned)f2b(v1) << 16) | f2b(v0);
            pk.y = ((unsigned)f2b(v3) << 16) | f2b(v2);
            if (MODE == 0) {
                // y1 half-planes: half = m>>1, within-half co = (m&1)*16+kg*4
                u16* dst = outp + ((size_t)(b * 2 + (m >> 1)) * PS + POFF + slot) * 32
                                + (m & 1) * 16 + kg * 4;
                *(uint2*)dst = pk;
            } else {
                // compact y2 [b][pix][64]
                u16* dst = outp + ((size_t)b * HW2 + pix) * 64 + m * 16 + kg * 4;
                *(uint2*)dst = pk;
            }
        }
    }
#pragma unroll
    for (int off = 1; off < 16; off <<= 1) {
#pragma unroll
        for (int m = 0; m < 4; ++m)
#pragma unroll
            for (int q = 0; q < 4; ++q) {
                s_[m][q] += __shfl_xor(s_[m][q], off);
                sq[m][q] += __shfl_xor(sq[m][q], off);
            }
    }
    __syncthreads();                     // bt reads done; reuse as reduce buffer
    float* red = (float*)bt;             // 7 waves x 128 floats
    if (px == 0) {
#pragma unroll
        for (int m = 0; m < 4; ++m)
#pragma unroll
            for (int q = 0; q < 4; ++q) {
                int c = m * 16 + kg * 4 + q;
                red[wave * 128 + c]      = s_[m][q];
                red[wave * 128 + 64 + c] = sq[m][q];
            }
    }
    __syncthreads();
    if (tid < 128) {
        float t = 0.f;
#pragma unroll
        for (int k = 0; k < 7; ++k) t += red[k * 128 + tid];
        atomicAdd(&sums[tid], t);
    }
}

// both weights: [b][co][ci][3][3] f32 -> [b][half][tap][kq][co][8ci] bf16.
// Extra trailing block zeroes the stats area.
__global__ __launch_bounds__(256)
void repack2_kernel(const float* __restrict__ w1, const float* __restrict__ w2,
                    u16* __restrict__ wt1, u16* __restrict__ wt2,
                    float* __restrict__ st)
{
    if (blockIdx.x == 9216) {
        st[threadIdx.x] = 0.f;           // 256 floats (sums1 + sums2)
        return;
    }
    int i = blockIdx.x * 256 + threadIdx.x;      // 0..2359295
    const int N = NB * 36864;
    const float* w = (i < N) ? w1 : w2;
    u16* wt = (i < N) ? wt1 : wt2;
    int o = (i < N) ? i : i - N;
    int b = o / 36864, r = o - b * 36864;
    int half = r / 18432; r -= half * 18432;
    int tap  = r / 2048;  r -= tap * 2048;
    int kq   = r / 512;   r -= kq * 512;
    int co   = r / 8;
    int ci   = half * 32 + kq * 8 + (r & 7);
    wt[o] = f2b(w[(((size_t)b * 64 + co) * 64 + ci) * 9 + tap]);
}

// out = relu(bn2(y2) + x), NCHW f32 via LDS transpose; y2 compact [b][pix][64]
__global__ __launch_bounds__(256)
void finalize_kernel(const u16* __restrict__ y2, const float* __restrict__ sums,
                     const float* __restrict__ gamma, const float* __restrict__ beta,
                     const float* __restrict__ x, float* __restrict__ out)
{
    __shared__ float lt[64][116];
    __shared__ float sbl[128];
    const int b = blockIdx.y, y = blockIdx.x;
    const int tid = threadIdx.x;
    if (tid < 64) {
        float mean = sums[tid] * (1.f / NPC);
        float var  = sums[64 + tid] * (1.f / NPC) - mean * mean;
        float sc   = gamma[tid] * rsqrtf(var + 1e-5f);
        sbl[tid]      = sc;
        sbl[64 + tid] = beta[tid] - mean * sc;
    }
    __syncthreads();
    const u16* rowp = y2 + ((size_t)b * HW2 + (size_t)y * HW) * 64;
    {
        const int cg = tid & 7;
        float sc[8], bi[8];
#pragma unroll
        for (int e = 0; e < 8; ++e) { sc[e] = sbl[cg * 8 + e]; bi[e] = sbl[64 + cg * 8 + e]; }
        for (int t = tid; t < HW * 8; t += 256) {
            int px = t >> 3;
            bf16x8 v = *(const bf16x8*)(rowp + px * 64 + cg * 8);
#pragma unroll
            for (int e = 0; e < 8; ++e)
                lt[cg * 8 + e][px] = b2f((u16)v[e]) * sc[e] + bi[e];
        }
    }
    __syncthreads();
    {
        const int c = tid >> 2, xg = (tid & 3) * 28;
        size_t base = ((size_t)b * CH + c) * HW2 + (size_t)y * HW + xg;
#pragma unroll
        for (int i = 0; i < 7; ++i) {
            float4 xv = *(const float4*)(x + base + i * 4);
            float4 r;
            r.x = fmaxf(lt[c][xg + i * 4 + 0] + xv.x, 0.f);
            r.y = fmaxf(lt[c][xg + i * 4 + 1] + xv.y, 0.f);
            r.z = fmaxf(lt[c][xg + i * 4 + 2] + xv.z, 0.f);
            r.w = fmaxf(lt[c][xg + i * 4 + 3] + xv.w, 0.f);
            *(float4*)(out + base + i * 4) = r;
        }
    }
}

extern "C" void kernel_launch(void* const* d_in, const int* in_sizes, int n_in,
                              void* d_out, int out_size, void* d_ws, size_t ws_size,
                              hipStream_t stream)
{
    const float* x  = (const float*)d_in[0];
    const float* w1 = (const float*)d_in[1];
    const float* w2 = (const float*)d_in[2];
    const float* g1 = (const float*)d_in[3];
    const float* b1 = (const float*)d_in[4];
    const float* g2 = (const float*)d_in[5];
    const float* b2 = (const float*)d_in[6];
    float* out = (float*)d_out;

    // ws: y2 compact (51.4MB) at 0; stats at +56MB.
    char* ws = (char*)d_ws;
    u16*   y2c  = (u16*)ws;
    float* st   = (float*)(ws + (size_t)(56u << 20));
    float* sums1 = st, *sums2 = st + 128;
    // d_out hosts y1 half-planes + repacked weights; dead before finalize writes.
    char*  oc   = (char*)d_out;
    u16*   y1p  = (u16*)oc;                            // 53.5 MB
    u16*   wt1  = (u16*)(oc + (size_t)(54u << 20));    // 2.25 MB
    u16*   wt2  = (u16*)(oc + (size_t)(58u << 20));    // 2.25 MB

    repack2_kernel<<<9217, 256, 0, stream>>>(w1, w2, wt1, wt2, st);

    conv_mfma<0><<<512, 448, 0, stream>>>(x, nullptr, wt1, y1p, sums1, st, g1, b1);
    conv_mfma<1><<<512, 448, 0, stream>>>(nullptr, y1p, wt2, y2c, sums2, sums1, g1, b1);
    finalize_kernel<<<dim3(112, 32), 256, 0, stream>>>(y2c, sums2, g2, b2, x, out);
}